// Round 1
// baseline (514.711 us; speedup 1.0000x reference)
//
#include <hip/hip_runtime.h>
#include <hip/hip_bf16.h>
#include <stdint.h>

typedef __attribute__((ext_vector_type(8))) short bf16x8;
typedef __attribute__((ext_vector_type(4))) float f32x4;

#define DEV static __device__ __forceinline__

// RNE f32 -> bf16 (finite inputs)
DEV unsigned short f2bf(float f) {
  union { float f; uint32_t u; } a; a.f = f;
  uint32_t u = a.u;
  return (unsigned short)((u + 0x7FFFu + ((u >> 16) & 1u)) >> 16);
}

DEV void gll16(const void* g, void* l) {
  __builtin_amdgcn_global_load_lds((const __attribute__((address_space(1))) void*)g,
                                   (__attribute__((address_space(3))) void*)l,
                                   16, 0, 0);
}

// ---------------- fp32 -> bf16 conversion ----------------
__global__ __launch_bounds__(256) void cvt_kernel(const float* __restrict__ src,
                                                  unsigned short* __restrict__ dst,
                                                  int n4) {
  int i = blockIdx.x * 256 + threadIdx.x;
  if (i >= n4) return;
  float4 f = reinterpret_cast<const float4*>(src)[i];
  ushort4 o;
  o.x = f2bf(f.x); o.y = f2bf(f.y); o.z = f2bf(f.z); o.w = f2bf(f.w);
  reinterpret_cast<ushort4*>(dst)[i] = o;
}

// ---------------- C[m][n] = sum_k A[m][k] * B[n][k]  (B^T GEMM, m97 structure) ----------------
DEV void storeC(float* p, float v) { *p = v; }
DEV void storeC(unsigned short* p, float v) { *p = f2bf(v); }

template <typename OutT>
__global__ __launch_bounds__(256) void gemm_bt(const unsigned short* __restrict__ A,
                                               const unsigned short* __restrict__ B,
                                               OutT* __restrict__ C,
                                               int M, int N, int K) {
  __shared__ unsigned short As[128 * 32];
  __shared__ unsigned short Bs[128 * 32];
  const int tid = threadIdx.x;
  const int lane = tid & 63;
  const int wave = tid >> 6;
  const int bm = blockIdx.x, bn = blockIdx.y;
  const int wr = wave >> 1, wc = wave & 1;   // 2x2 wave grid, 64x64 per wave
  const int lrow = lane >> 2, lch = lane & 3;
  const int fr = lane & 15, fg = lane >> 4;

  f32x4 acc[4][4];
#pragma unroll
  for (int m = 0; m < 4; ++m)
#pragma unroll
    for (int n = 0; n < 4; ++n) acc[m][n] = (f32x4){0.f, 0.f, 0.f, 0.f};

  const unsigned short* ga0 = A + (size_t)(bm * 128 + wave * 32 + lrow) * K + lch * 8;
  const unsigned short* gb0 = B + (size_t)(bn * 128 + wave * 32 + lrow) * K + lch * 8;
  char* la0 = (char*)As + wave * 32 * 64;  // 64B rows, wave-uniform base (+lane*16 by HW)
  char* lb0 = (char*)Bs + wave * 32 * 64;

  for (int k0 = 0; k0 < K; k0 += 32) {
    gll16(ga0 + k0, la0);
    gll16(ga0 + k0 + 16 * K, la0 + 16 * 64);
    gll16(gb0 + k0, lb0);
    gll16(gb0 + k0 + 16 * K, lb0 + 16 * 64);
    __syncthreads();
    bf16x8 af[4], bfr[4];
#pragma unroll
    for (int m = 0; m < 4; ++m)
      af[m] = *(const bf16x8*)((const char*)As + (wr * 64 + m * 16 + fr) * 64 + fg * 16);
#pragma unroll
    for (int n = 0; n < 4; ++n)
      bfr[n] = *(const bf16x8*)((const char*)Bs + (wc * 64 + n * 16 + fr) * 64 + fg * 16);
#pragma unroll
    for (int m = 0; m < 4; ++m)
#pragma unroll
      for (int n = 0; n < 4; ++n)
        acc[m][n] = __builtin_amdgcn_mfma_f32_16x16x32_bf16(af[m], bfr[n], acc[m][n], 0, 0, 0);
    __syncthreads();
  }

#pragma unroll
  for (int m = 0; m < 4; ++m)
#pragma unroll
    for (int n = 0; n < 4; ++n)
#pragma unroll
      for (int r = 0; r < 4; ++r) {
        const int row = bm * 128 + wr * 64 + m * 16 + fg * 4 + r;
        const int col = bn * 128 + wc * 64 + n * 16 + fr;
        storeC(&C[(size_t)row * N + col], acc[m][n][r]);
      }
}

// ---------------- causal GQA flash attention ----------------
// grid (S/64, H=16, B=2); block 256 = 4 waves; wave w owns q rows q0+16w..+15.
// Swapped QK: ST = mfma(K, Q) -> lane holds q = lane&15, kv = 4*(lane>>4)+reg.
// PV: attn^T = mfma(V^T, P^T).
__global__ __launch_bounds__(256) void attn_kernel(const unsigned short* __restrict__ qb,
                                                   const unsigned short* __restrict__ kb,
                                                   const unsigned short* __restrict__ vb,
                                                   unsigned short* __restrict__ ob) {
  const int S = 2048;
  __shared__ unsigned short Ks[64 * 128];   // linear rows of 256B, chunk-swizzled content
  __shared__ unsigned short Vt[128 * 72];   // V^T, rows padded to 72 elems (144B, 16B-aligned)
  const int tid = threadIdx.x;
  const int lane = tid & 63;
  const int wave = tid >> 6;
  const int b = blockIdx.z, h = blockIdx.y;
  const int q0 = blockIdx.x * 64;
  const int kvh = h >> 2;                   // rep = H/KV = 4
  const int c = lane & 15, g = lane >> 4;
  const int q0w = q0 + wave * 16;
  const int qg = q0w + c;

  // Q fragments (B-operand of swapped QK): lane holds Q[q0w+c][32*kk + 8g .. +7]
  bf16x8 qf[4];
  {
    const unsigned short* qp = qb + ((size_t)(b * S + q0w + c) * 16 + h) * 128 + g * 8;
#pragma unroll
    for (int kk = 0; kk < 4; ++kk) qf[kk] = *(const bf16x8*)(qp + kk * 32);
  }
  f32x4 oacc[8];   // attn^T: d = 16*nd + 4g + reg, q = c
#pragma unroll
  for (int nd = 0; nd < 8; ++nd) oacc[nd] = (f32x4){0.f, 0.f, 0.f, 0.f};
  float m_run = -1e30f, l_run = 0.f;
  const float SCALE = 0.08838834764831845f;  // 1/sqrt(128)

  const int ntile = q0 / 64 + 1;
  for (int t = 0; t < ntile; ++t) {
    const int kv0 = t * 64;
    __syncthreads();   // previous tile's LDS reads done before overwrite
    // ---- stage K: global_load_lds, source chunk pre-swizzled (involution c ^= row&7) ----
#pragma unroll
    for (int i = 0; i < 4; ++i) {
      const int r0 = (i * 4 + wave) * 4;   // 4 rows (1KB) per wave-issue
      const int row = r0 + g;
      const int ch = c ^ (row & 7);
      const unsigned short* gk = kb + (size_t)(b * S + kv0 + row) * 512 + kvh * 128 + ch * 8;
      gll16(gk, (char*)Ks + r0 * 256);
    }
    // ---- stage V^T: reg-staged transpose ----
#pragma unroll
    for (int ii = 0; ii < 4; ++ii) {
      const int d0 = wave * 32 + ii * 8;
      const unsigned short* gv = vb + (size_t)(b * S + kv0 + lane) * 512 + kvh * 128 + d0;
      union { int4 i4; unsigned short u[8]; } vv;
      vv.i4 = *(const int4*)gv;
#pragma unroll
      for (int j = 0; j < 8; ++j) Vt[(d0 + j) * 72 + lane] = vv.u[j];
    }
    __syncthreads();
    // ---- compute ----
    int nbp = (q0w + 16 - kv0) >> 4;            // # of 16-kv blocks this wave needs
    nbp = nbp < 0 ? 0 : (nbp > 4 ? 4 : nbp);
    if (nbp > 0) {
      f32x4 p[4];
#pragma unroll
      for (int nb = 0; nb < 4; ++nb) p[nb] = (f32x4){0.f, 0.f, 0.f, 0.f};
      const bool dm = (kv0 + 63 > q0w);
#pragma unroll
      for (int nb = 0; nb < 4; ++nb)
        if (nb < nbp) {
          f32x4 s = (f32x4){0.f, 0.f, 0.f, 0.f};
#pragma unroll
          for (int kk = 0; kk < 4; ++kk) {
            const int row = nb * 16 + c;
            const int colB = (kk * 64 + g * 16) ^ ((row & 7) << 4);
            bf16x8 kf = *(const bf16x8*)((const char*)Ks + row * 256 + colB);
            s = __builtin_amdgcn_mfma_f32_16x16x32_bf16(kf, qf[kk], s, 0, 0, 0);
          }
#pragma unroll
          for (int r = 0; r < 4; ++r) {
            float sv = s[r] * SCALE;
            if (dm && (kv0 + nb * 16 + g * 4 + r > qg)) sv = -1e30f;
            p[nb][r] = sv;
          }
        }
      // online softmax (per-q state lane-local; reduce over 4 lanes sharing c)
      float rmax = -1e30f;
#pragma unroll
      for (int nb = 0; nb < 4; ++nb)
        if (nb < nbp)
#pragma unroll
          for (int r = 0; r < 4; ++r) rmax = fmaxf(rmax, p[nb][r]);
      rmax = fmaxf(rmax, __shfl_xor(rmax, 16));
      rmax = fmaxf(rmax, __shfl_xor(rmax, 32));
      const float mnew = fmaxf(m_run, rmax);
      const float alpha = __expf(m_run - mnew);
      float rs = 0.f;
#pragma unroll
      for (int nb = 0; nb < 4; ++nb)
        if (nb < nbp)
#pragma unroll
          for (int r = 0; r < 4; ++r) {
            const float e = __expf(p[nb][r] - mnew);
            p[nb][r] = e;
            rs += e;
          }
      rs += __shfl_xor(rs, 16);
      rs += __shfl_xor(rs, 32);
      l_run = l_run * alpha + rs;
      m_run = mnew;
#pragma unroll
      for (int nd = 0; nd < 8; ++nd) oacc[nd] *= alpha;
      // ---- PV over two 32-kv windows ----
#pragma unroll
      for (int w = 0; w < 2; ++w)
        if (w * 2 < nbp) {
          union { bf16x8 v; unsigned short u[8]; } pf;
#pragma unroll
          for (int j = 0; j < 8; ++j) {
            const int kl = g * 8 + j;                      // kv within window
            const int src = c + (((kl >> 2) & 3) << 4);    // source lane
            const float a0 = __shfl(p[w * 2 + 0][j & 3], src);
            const float a1 = __shfl(p[w * 2 + 1][j & 3], src);
            pf.u[j] = f2bf((kl & 16) ? a1 : a0);
          }
#pragma unroll
          for (int nd = 0; nd < 8; ++nd) {
            bf16x8 vf = *(const bf16x8*)((const char*)Vt +
                          ((nd * 16 + c) * 72 + w * 32 + g * 8) * 2);
            oacc[nd] = __builtin_amdgcn_mfma_f32_16x16x32_bf16(vf, pf.v, oacc[nd], 0, 0, 0);
          }
        }
    }
  }
  // epilogue: attn[b, q, h, d] = oacc / l
  const float inv = 1.f / l_run;
  unsigned short* op = ob + ((size_t)(b * S + qg) * 16 + h) * 128;
#pragma unroll
  for (int nd = 0; nd < 8; ++nd)
#pragma unroll
    for (int r = 0; r < 4; ++r)
      op[nd * 16 + g * 4 + r] = f2bf(oacc[nd][r] * inv);
}

// ---------------- launch ----------------
extern "C" void kernel_launch(void* const* d_in, const int* in_sizes, int n_in,
                              void* d_out, int out_size, void* d_ws, size_t ws_size,
                              hipStream_t stream) {
  (void)in_sizes; (void)n_in; (void)out_size; (void)ws_size;
  const float* x  = (const float*)d_in[0];
  const float* Wq = (const float*)d_in[1];
  const float* Wk = (const float*)d_in[2];
  const float* Wv = (const float*)d_in[3];
  const float* Wo = (const float*)d_in[4];
  float* out = (float*)d_out;

  const int B = 2, S = 2048, E = 2048;
  const int M = B * S;              // 4096
  const int KVDIM = 512;            // KV * D

  char* p = (char*)d_ws;
  unsigned short* xb   = (unsigned short*)p; p += (size_t)M * E * 2;
  unsigned short* wqb  = (unsigned short*)p; p += (size_t)E * E * 2;
  unsigned short* wkb  = (unsigned short*)p; p += (size_t)KVDIM * E * 2;
  unsigned short* wvb  = (unsigned short*)p; p += (size_t)KVDIM * E * 2;
  unsigned short* wob  = (unsigned short*)p; p += (size_t)E * E * 2;
  unsigned short* qbuf = (unsigned short*)p; p += (size_t)M * E * 2;
  unsigned short* kbuf = (unsigned short*)p; p += (size_t)M * KVDIM * 2;
  unsigned short* vbuf = (unsigned short*)p; p += (size_t)M * KVDIM * 2;
  unsigned short* abuf = (unsigned short*)p; p += (size_t)M * E * 2;

  {
    int n4;
    n4 = (M * E) / 4;     cvt_kernel<<<(n4 + 255) / 256, 256, 0, stream>>>(x,  xb,  n4);
    n4 = (E * E) / 4;     cvt_kernel<<<(n4 + 255) / 256, 256, 0, stream>>>(Wq, wqb, n4);
    n4 = (KVDIM * E) / 4; cvt_kernel<<<(n4 + 255) / 256, 256, 0, stream>>>(Wk, wkb, n4);
    n4 = (KVDIM * E) / 4; cvt_kernel<<<(n4 + 255) / 256, 256, 0, stream>>>(Wv, wvb, n4);
    n4 = (E * E) / 4;     cvt_kernel<<<(n4 + 255) / 256, 256, 0, stream>>>(Wo, wob, n4);
  }

  dim3 blk(256);
  gemm_bt<unsigned short><<<dim3(M / 128, E / 128),     blk, 0, stream>>>(xb, wqb, qbuf, M, E, E);
  gemm_bt<unsigned short><<<dim3(M / 128, KVDIM / 128), blk, 0, stream>>>(xb, wkb, kbuf, M, KVDIM, E);
  gemm_bt<unsigned short><<<dim3(M / 128, KVDIM / 128), blk, 0, stream>>>(xb, wvb, vbuf, M, KVDIM, E);
  attn_kernel<<<dim3(S / 64, 16, B), blk, 0, stream>>>(qbuf, kbuf, vbuf, abuf);
  gemm_bt<float><<<dim3(M / 128, E / 128), blk, 0, stream>>>(abuf, wob, out, M, E, E);
}

// Round 5
// 350.872 us; speedup vs baseline: 1.4670x; 1.4670x over previous
//
#include <hip/hip_runtime.h>
#include <hip/hip_bf16.h>
#include <stdint.h>

typedef __attribute__((ext_vector_type(8))) short bf16x8;
typedef __attribute__((ext_vector_type(4))) float f32x4;

#define DEV static __device__ __forceinline__

// RNE f32 -> bf16 (finite inputs)
DEV unsigned short f2bf(float f) {
  union { float f; uint32_t u; } a; a.f = f;
  uint32_t u = a.u;
  return (unsigned short)((u + 0x7FFFu + ((u >> 16) & 1u)) >> 16);
}

DEV void gll16(const void* g, void* l) {
  __builtin_amdgcn_global_load_lds((const __attribute__((address_space(1))) void*)g,
                                   (__attribute__((address_space(3))) void*)l,
                                   16, 0, 0);
}

// ---------------- fp32 -> bf16 conversion ----------------
__global__ __launch_bounds__(256) void cvt_kernel(const float* __restrict__ src,
                                                  unsigned short* __restrict__ dst,
                                                  int n4) {
  int i = blockIdx.x * 256 + threadIdx.x;
  if (i >= n4) return;
  float4 f = reinterpret_cast<const float4*>(src)[i];
  ushort4 o;
  o.x = f2bf(f.x); o.y = f2bf(f.y); o.z = f2bf(f.z); o.w = f2bf(f.w);
  reinterpret_cast<ushort4*>(dst)[i] = o;
}

// ---------------- C[m][n] = sum_k A[m][k] * B[n][k]  (B^T GEMM, m97 structure) ----------------
DEV void storeC(float* p, float v) { *p = v; }
DEV void storeC(unsigned short* p, float v) { *p = f2bf(v); }

template <typename OutT>
__global__ __launch_bounds__(256) void gemm_bt(const unsigned short* __restrict__ A,
                                               const unsigned short* __restrict__ B,
                                               OutT* __restrict__ C,
                                               int M, int N, int K) {
  __shared__ unsigned short As[128 * 32];
  __shared__ unsigned short Bs[128 * 32];
  const int tid = threadIdx.x;
  const int lane = tid & 63;
  const int wave = tid >> 6;
  const int bm = blockIdx.x, bn = blockIdx.y;
  const int wr = wave >> 1, wc = wave & 1;   // 2x2 wave grid, 64x64 per wave
  const int lrow = lane >> 2, lch = lane & 3;
  const int fr = lane & 15, fg = lane >> 4;

  f32x4 acc[4][4];
#pragma unroll
  for (int m = 0; m < 4; ++m)
#pragma unroll
    for (int n = 0; n < 4; ++n) acc[m][n] = (f32x4){0.f, 0.f, 0.f, 0.f};

  const unsigned short* ga0 = A + (size_t)(bm * 128 + wave * 32 + lrow) * K + lch * 8;
  const unsigned short* gb0 = B + (size_t)(bn * 128 + wave * 32 + lrow) * K + lch * 8;
  char* la0 = (char*)As + wave * 32 * 64;  // 64B rows, wave-uniform base (+lane*16 by HW)
  char* lb0 = (char*)Bs + wave * 32 * 64;

  for (int k0 = 0; k0 < K; k0 += 32) {
    gll16(ga0 + k0, la0);
    gll16(ga0 + k0 + 16 * K, la0 + 16 * 64);
    gll16(gb0 + k0, lb0);
    gll16(gb0 + k0 + 16 * K, lb0 + 16 * 64);
    __syncthreads();
    bf16x8 af[4], bfr[4];
#pragma unroll
    for (int m = 0; m < 4; ++m)
      af[m] = *(const bf16x8*)((const char*)As + (wr * 64 + m * 16 + fr) * 64 + fg * 16);
#pragma unroll
    for (int n = 0; n < 4; ++n)
      bfr[n] = *(const bf16x8*)((const char*)Bs + (wc * 64 + n * 16 + fr) * 64 + fg * 16);
#pragma unroll
    for (int m = 0; m < 4; ++m)
#pragma unroll
      for (int n = 0; n < 4; ++n)
        acc[m][n] = __builtin_amdgcn_mfma_f32_16x16x32_bf16(af[m], bfr[n], acc[m][n], 0, 0, 0);
    __syncthreads();
  }

#pragma unroll
  for (int m = 0; m < 4; ++m)
#pragma unroll
    for (int n = 0; n < 4; ++n)
#pragma unroll
      for (int r = 0; r < 4; ++r) {
        const int row = bm * 128 + wr * 64 + m * 16 + fg * 4 + r;
        const int col = bn * 128 + wc * 64 + n * 16 + fr;
        storeC(&C[(size_t)row * N + col], acc[m][n][r]);
      }
}

// ---------------- causal GQA flash attention, paired q-tiles ----------------
// grid (16, H=16, B=2); block 256 = 4 waves. Block ti handles q-tiles ti and 31-ti
// of the same (b,h); each staged KV tile is consumed by both -> perfect balance
// (33 tile-computes/block) + 2x staging amortization.
// Input is the packed QKV buffer: row stride 3072 = [Q 2048 | K 512 | V 512].
// Swapped QK: ST = mfma(K, Q) -> lane holds q = lane&15, kv = 4*(lane>>4)+reg.
// PV: attn^T = mfma(V^T, P^T).

DEV void attn_tile(const unsigned short* __restrict__ Ks,
                   const unsigned short* __restrict__ Vt,
                   const bf16x8 qf[4], f32x4 oacc[8],
                   float& m_run, float& l_run,
                   int kv0, int q0w, int c, int g) {
  const float SCALE = 0.08838834764831845f;  // 1/sqrt(128)
  const int qg = q0w + c;
  int nbp = (q0w + 16 - kv0) >> 4;            // # of 16-kv blocks this wave needs
  nbp = nbp < 0 ? 0 : (nbp > 4 ? 4 : nbp);
  if (nbp <= 0) return;

  f32x4 p[4];
#pragma unroll
  for (int nb = 0; nb < 4; ++nb) p[nb] = (f32x4){0.f, 0.f, 0.f, 0.f};
  const bool dm = (kv0 + 63 > q0w);
#pragma unroll
  for (int nb = 0; nb < 4; ++nb)
    if (nb < nbp) {
      f32x4 s = (f32x4){0.f, 0.f, 0.f, 0.f};
#pragma unroll
      for (int kk = 0; kk < 4; ++kk) {
        const int row = nb * 16 + c;
        const int colB = (kk * 64 + g * 16) ^ ((row & 7) << 4);
        bf16x8 kf = *(const bf16x8*)((const char*)Ks + row * 256 + colB);
        s = __builtin_amdgcn_mfma_f32_16x16x32_bf16(kf, qf[kk], s, 0, 0, 0);
      }
#pragma unroll
      for (int r = 0; r < 4; ++r) {
        float sv = s[r] * SCALE;
        if (dm && (kv0 + nb * 16 + g * 4 + r > qg)) sv = -1e30f;
        p[nb][r] = sv;
      }
    }
  // online softmax (per-q state lane-local; reduce over 4 lanes sharing c)
  float rmax = -1e30f;
#pragma unroll
  for (int nb = 0; nb < 4; ++nb)
    if (nb < nbp)
#pragma unroll
      for (int r = 0; r < 4; ++r) rmax = fmaxf(rmax, p[nb][r]);
  rmax = fmaxf(rmax, __shfl_xor(rmax, 16));
  rmax = fmaxf(rmax, __shfl_xor(rmax, 32));
  const float mnew = fmaxf(m_run, rmax);
  const float alpha = __expf(m_run - mnew);
  float rs = 0.f;
#pragma unroll
  for (int nb = 0; nb < 4; ++nb)
    if (nb < nbp)
#pragma unroll
      for (int r = 0; r < 4; ++r) {
        const float e = __expf(p[nb][r] - mnew);
        p[nb][r] = e;
        rs += e;
      }
  rs += __shfl_xor(rs, 16);
  rs += __shfl_xor(rs, 32);
  l_run = l_run * alpha + rs;
  m_run = mnew;
#pragma unroll
  for (int nd = 0; nd < 8; ++nd) oacc[nd] *= alpha;
  // ---- PV over two 32-kv windows ----
#pragma unroll
  for (int w = 0; w < 2; ++w)
    if (w * 2 < nbp) {
      union { bf16x8 v; unsigned short u[8]; } pf;
#pragma unroll
      for (int j = 0; j < 8; ++j) {
        const int kl = g * 8 + j;                      // kv within window
        const int src = c + (((kl >> 2) & 3) << 4);    // source lane
        const float a0 = __shfl(p[w * 2 + 0][j & 3], src);
        const float a1 = __shfl(p[w * 2 + 1][j & 3], src);
        pf.u[j] = f2bf((kl & 16) ? a1 : a0);
      }
#pragma unroll
      for (int nd = 0; nd < 8; ++nd) {
        bf16x8 vf = *(const bf16x8*)((const char*)Vt +
                      ((nd * 16 + c) * 72 + w * 32 + g * 8) * 2);
        oacc[nd] = __builtin_amdgcn_mfma_f32_16x16x32_bf16(vf, pf.v, oacc[nd], 0, 0, 0);
      }
    }
}

__global__ __launch_bounds__(256) void attn_kernel(const unsigned short* __restrict__ qkv,
                                                   unsigned short* __restrict__ ob) {
  const int S = 2048;
  const int QKVS = 3072;                    // packed row stride
  __shared__ unsigned short Ks[64 * 128];   // linear rows of 256B, chunk-swizzled content
  __shared__ unsigned short Vt[128 * 72];   // V^T, rows padded to 72 elems (144B, 16B-aligned)
  const int tid = threadIdx.x;
  const int lane = tid & 63;
  const int wave = tid >> 6;
  const int b = blockIdx.z, h = blockIdx.y;
  const int tiA = blockIdx.x, tiB = 31 - tiA;
  const int kvh = h >> 2;                   // rep = H/KV = 4
  const int c = lane & 15, g = lane >> 4;
  const int q0Aw = tiA * 64 + wave * 16;
  const int q0Bw = tiB * 64 + wave * 16;

  // Q fragments for both tiles (B-operand of swapped QK)
  bf16x8 qfA[4], qfB[4];
  {
    const unsigned short* qpA = qkv + (size_t)(b * S + q0Aw + c) * QKVS + h * 128 + g * 8;
    const unsigned short* qpB = qkv + (size_t)(b * S + q0Bw + c) * QKVS + h * 128 + g * 8;
#pragma unroll
    for (int kk = 0; kk < 4; ++kk) {
      qfA[kk] = *(const bf16x8*)(qpA + kk * 32);
      qfB[kk] = *(const bf16x8*)(qpB + kk * 32);
    }
  }
  f32x4 oaccA[8], oaccB[8];   // attn^T: d = 16*nd + 4g + reg, q = c
#pragma unroll
  for (int nd = 0; nd < 8; ++nd) {
    oaccA[nd] = (f32x4){0.f, 0.f, 0.f, 0.f};
    oaccB[nd] = (f32x4){0.f, 0.f, 0.f, 0.f};
  }
  float mA = -1e30f, lA = 0.f, mB = -1e30f, lB = 0.f;

  const int ntile = tiB + 1;
  for (int t = 0; t < ntile; ++t) {
    const int kv0 = t * 64;
    __syncthreads();   // previous tile's LDS reads done before overwrite
    // ---- stage K: global_load_lds, source chunk pre-swizzled (involution c ^= row&7) ----
#pragma unroll
    for (int i = 0; i < 4; ++i) {
      const int r0 = i * 16 + wave * 4;   // 4 rows (1KB) per wave-issue
      const int row = r0 + g;
      const int ch = c ^ (row & 7);
      const unsigned short* gk = qkv + (size_t)(b * S + kv0 + row) * QKVS + 2048 + kvh * 128 + ch * 8;
      gll16(gk, (char*)Ks + r0 * 256);
    }
    // ---- stage V^T: reg-staged transpose ----
#pragma unroll
    for (int ii = 0; ii < 4; ++ii) {
      const int d0 = wave * 32 + ii * 8;
      const unsigned short* gv = qkv + (size_t)(b * S + kv0 + lane) * QKVS + 2560 + kvh * 128 + d0;
      union { int4 i4; unsigned short u[8]; } vv;
      vv.i4 = *(const int4*)gv;
#pragma unroll
      for (int j = 0; j < 8; ++j) Vt[(d0 + j) * 72 + lane] = vv.u[j];
    }
    __syncthreads();
    // ---- compute: tile A (while in causal range), then tile B (always) ----
    if (t <= tiA) attn_tile(Ks, Vt, qfA, oaccA, mA, lA, kv0, q0Aw, c, g);
    attn_tile(Ks, Vt, qfB, oaccB, mB, lB, kv0, q0Bw, c, g);
  }

  // epilogue: attn[b, q, h, d] = oacc / l
  {
    const float inv = 1.f / lA;
    unsigned short* op = ob + ((size_t)(b * S + q0Aw + c) * 16 + h) * 128;
#pragma unroll
    for (int nd = 0; nd < 8; ++nd)
#pragma unroll
      for (int r = 0; r < 4; ++r)
        op[nd * 16 + g * 4 + r] = f2bf(oaccA[nd][r] * inv);
  }
  {
    const float inv = 1.f / lB;
    unsigned short* op = ob + ((size_t)(b * S + q0Bw + c) * 16 + h) * 128;
#pragma unroll
    for (int nd = 0; nd < 8; ++nd)
#pragma unroll
      for (int r = 0; r < 4; ++r)
        op[nd * 16 + g * 4 + r] = f2bf(oaccB[nd][r] * inv);
  }
}

// ---------------- launch ----------------
extern "C" void kernel_launch(void* const* d_in, const int* in_sizes, int n_in,
                              void* d_out, int out_size, void* d_ws, size_t ws_size,
                              hipStream_t stream) {
  (void)in_sizes; (void)n_in; (void)out_size; (void)ws_size;
  const float* x  = (const float*)d_in[0];
  const float* Wq = (const float*)d_in[1];
  const float* Wk = (const float*)d_in[2];
  const float* Wv = (const float*)d_in[3];
  const float* Wo = (const float*)d_in[4];
  float* out = (float*)d_out;

  const int B = 2, S = 2048, E = 2048;
  const int M = B * S;              // 4096
  const int KVDIM = 512;            // KV * D
  const int NQKV = E + 2 * KVDIM;   // 3072 packed

  char* p = (char*)d_ws;
  unsigned short* xb   = (unsigned short*)p; p += (size_t)M * E * 2;
  // wqb/wkb/wvb MUST stay contiguous in this order: they form the fused
  // B-operand (rows = output features of Wq || Wk || Wv).
  unsigned short* wqb  = (unsigned short*)p; p += (size_t)E * E * 2;
  unsigned short* wkb  = (unsigned short*)p; p += (size_t)KVDIM * E * 2;
  unsigned short* wvb  = (unsigned short*)p; p += (size_t)KVDIM * E * 2;
  unsigned short* wob  = (unsigned short*)p; p += (size_t)E * E * 2;
  unsigned short* qkvbuf = (unsigned short*)p; p += (size_t)M * NQKV * 2;  // packed per-row [Q|K|V]
  unsigned short* abuf   = (unsigned short*)p; p += (size_t)M * E * 2;

  {
    int n4;
    n4 = (M * E) / 4;     cvt_kernel<<<(n4 + 255) / 256, 256, 0, stream>>>(x,  xb,  n4);
    n4 = (E * E) / 4;     cvt_kernel<<<(n4 + 255) / 256, 256, 0, stream>>>(Wq, wqb, n4);
    n4 = (KVDIM * E) / 4; cvt_kernel<<<(n4 + 255) / 256, 256, 0, stream>>>(Wk, wkb, n4);
    n4 = (KVDIM * E) / 4; cvt_kernel<<<(n4 + 255) / 256, 256, 0, stream>>>(Wv, wvb, n4);
    n4 = (E * E) / 4;     cvt_kernel<<<(n4 + 255) / 256, 256, 0, stream>>>(Wo, wob, n4);
  }

  dim3 blk(256);
  // fused QKV projection: grid 32x24 = 768 blocks (3/CU) vs 512+128+128
  gemm_bt<unsigned short><<<dim3(M / 128, NQKV / 128), blk, 0, stream>>>(xb, wqb, qkvbuf, M, NQKV, E);
  attn_kernel<<<dim3(16, 16, B), blk, 0, stream>>>(qkvbuf, abuf);
  gemm_bt<float><<<dim3(M / 128, E / 128), blk, 0, stream>>>(abuf, wob, out, M, E, E);
}

// Round 7
// 336.841 us; speedup vs baseline: 1.5281x; 1.0417x over previous
//
#include <hip/hip_runtime.h>
#include <hip/hip_bf16.h>
#include <stdint.h>

typedef __attribute__((ext_vector_type(8))) short bf16x8;
typedef __attribute__((ext_vector_type(4))) float f32x4;

#define DEV static __device__ __forceinline__

// RNE f32 -> bf16 (finite inputs)
DEV unsigned short f2bf(float f) {
  union { float f; uint32_t u; } a; a.f = f;
  uint32_t u = a.u;
  return (unsigned short)((u + 0x7FFFu + ((u >> 16) & 1u)) >> 16);
}

// hardware 2^x (v_exp_f32 IS exp2)
DEV float exp2_hw(float x) {
  float r;
  asm("v_exp_f32 %0, %1" : "=v"(r) : "v"(x));
  return r;
}

// pack two f32 -> 2xbf16 in one u32 (lo=first, hi=second)
DEV uint32_t pk_bf16(float lo, float hi) {
  uint32_t r;
  asm("v_cvt_pk_bf16_f32 %0, %1, %2" : "=v"(r) : "v"(lo), "v"(hi));
  return r;
}

DEV void gll16(const void* g, void* l) {
  __builtin_amdgcn_global_load_lds((const __attribute__((address_space(1))) void*)g,
                                   (__attribute__((address_space(3))) void*)l,
                                   16, 0, 0);
}

// ---------------- fp32 -> bf16 conversion ----------------
__global__ __launch_bounds__(256) void cvt_kernel(const float* __restrict__ src,
                                                  unsigned short* __restrict__ dst,
                                                  int n4) {
  int i = blockIdx.x * 256 + threadIdx.x;
  if (i >= n4) return;
  float4 f = reinterpret_cast<const float4*>(src)[i];
  ushort4 o;
  o.x = f2bf(f.x); o.y = f2bf(f.y); o.z = f2bf(f.z); o.w = f2bf(f.w);
  reinterpret_cast<ushort4*>(dst)[i] = o;
}

// ---------------- C[m][n] = sum_k A[m][k] * B[n][k]  (B^T GEMM, m97 structure) ----------------
DEV void storeC(float* p, float v) { *p = v; }
DEV void storeC(unsigned short* p, float v) { *p = f2bf(v); }

template <typename OutT>
__global__ __launch_bounds__(256) void gemm_bt(const unsigned short* __restrict__ A,
                                               const unsigned short* __restrict__ B,
                                               OutT* __restrict__ C,
                                               int M, int N, int K) {
  __shared__ unsigned short As[128 * 32];
  __shared__ unsigned short Bs[128 * 32];
  const int tid = threadIdx.x;
  const int lane = tid & 63;
  const int wave = tid >> 6;
  const int bm = blockIdx.x, bn = blockIdx.y;
  const int wr = wave >> 1, wc = wave & 1;   // 2x2 wave grid, 64x64 per wave
  const int lrow = lane >> 2, lch = lane & 3;
  const int fr = lane & 15, fg = lane >> 4;

  f32x4 acc[4][4];
#pragma unroll
  for (int m = 0; m < 4; ++m)
#pragma unroll
    for (int n = 0; n < 4; ++n) acc[m][n] = (f32x4){0.f, 0.f, 0.f, 0.f};

  const unsigned short* ga0 = A + (size_t)(bm * 128 + wave * 32 + lrow) * K + lch * 8;
  const unsigned short* gb0 = B + (size_t)(bn * 128 + wave * 32 + lrow) * K + lch * 8;
  char* la0 = (char*)As + wave * 32 * 64;  // 64B rows, wave-uniform base (+lane*16 by HW)
  char* lb0 = (char*)Bs + wave * 32 * 64;

  for (int k0 = 0; k0 < K; k0 += 32) {
    gll16(ga0 + k0, la0);
    gll16(ga0 + k0 + 16 * K, la0 + 16 * 64);
    gll16(gb0 + k0, lb0);
    gll16(gb0 + k0 + 16 * K, lb0 + 16 * 64);
    __syncthreads();
    bf16x8 af[4], bfr[4];
#pragma unroll
    for (int m = 0; m < 4; ++m)
      af[m] = *(const bf16x8*)((const char*)As + (wr * 64 + m * 16 + fr) * 64 + fg * 16);
#pragma unroll
    for (int n = 0; n < 4; ++n)
      bfr[n] = *(const bf16x8*)((const char*)Bs + (wc * 64 + n * 16 + fr) * 64 + fg * 16);
#pragma unroll
    for (int m = 0; m < 4; ++m)
#pragma unroll
      for (int n = 0; n < 4; ++n)
        acc[m][n] = __builtin_amdgcn_mfma_f32_16x16x32_bf16(af[m], bfr[n], acc[m][n], 0, 0, 0);
    __syncthreads();
  }

#pragma unroll
  for (int m = 0; m < 4; ++m)
#pragma unroll
    for (int n = 0; n < 4; ++n)
#pragma unroll
      for (int r = 0; r < 4; ++r) {
        const int row = bm * 128 + wr * 64 + m * 16 + fg * 4 + r;
        const int col = bn * 128 + wc * 64 + n * 16 + fr;
        storeC(&C[(size_t)row * N + col], acc[m][n][r]);
      }
}

// ---------------- causal GQA flash attention, paired q-tiles ----------------
// grid (16, H=16, B=2); block 256 = 4 waves. Block ti handles q-tiles ti and 31-ti
// of the same (b,h). Packed QKV input: row stride 3072 = [Q 2048 | K 512 | V 512].
// Swapped QK: ST = mfma(K, Q) -> lane holds q = lane&15, kv = 4*(lane>>4)+reg.
// Softmax in exp2 domain (v_exp_f32), defer-rescale THR=8 (log2).
// P transposed for PV via per-wave LDS buffer Pl[16][72] (replaces bpermute gather).
// PV: attn^T = mfma(V^T, P^T).

DEV void attn_tile(const unsigned short* __restrict__ Ks,
                   const unsigned short* __restrict__ Vt,
                   unsigned short* __restrict__ Plw,   // this wave's [16][72] bf16
                   const bf16x8 qf[4], f32x4 oacc[8],
                   float& m_run, float& l_run,
                   int kv0, int q0w, int c, int g) {
  const float SCALE2 = 0.12754296f;  // 1/sqrt(128) * log2(e)
  const int qg = q0w + c;
  int nbp = (q0w + 16 - kv0) >> 4;            // # of 16-kv blocks this wave needs
  nbp = nbp < 0 ? 0 : (nbp > 4 ? 4 : nbp);
  if (nbp <= 0) return;

  f32x4 p[4];
#pragma unroll
  for (int nb = 0; nb < 4; ++nb) p[nb] = (f32x4){0.f, 0.f, 0.f, 0.f};
  const bool dm = (kv0 + 63 > q0w);
  __builtin_amdgcn_s_setprio(1);
#pragma unroll
  for (int nb = 0; nb < 4; ++nb)
    if (nb < nbp) {
      f32x4 s = (f32x4){0.f, 0.f, 0.f, 0.f};
#pragma unroll
      for (int kk = 0; kk < 4; ++kk) {
        const int row = nb * 16 + c;
        const int colB = (kk * 64 + g * 16) ^ ((row & 7) << 4);
        bf16x8 kf = *(const bf16x8*)((const char*)Ks + row * 256 + colB);
        s = __builtin_amdgcn_mfma_f32_16x16x32_bf16(kf, qf[kk], s, 0, 0, 0);
      }
#pragma unroll
      for (int r = 0; r < 4; ++r) {
        float sv = s[r] * SCALE2;            // log2-domain score
        if (dm && (kv0 + nb * 16 + g * 4 + r > qg)) sv = -1e30f;
        p[nb][r] = sv;
      }
    }
  __builtin_amdgcn_s_setprio(0);
  // online softmax, exp2 domain (per-q state lane-local; reduce over 4 lanes sharing c)
  float rmax = -1e30f;
#pragma unroll
  for (int nb = 0; nb < 4; ++nb)
    if (nb < nbp)
#pragma unroll
      for (int r = 0; r < 4; ++r) rmax = fmaxf(rmax, p[nb][r]);
  rmax = fmaxf(rmax, __shfl_xor(rmax, 16));
  rmax = fmaxf(rmax, __shfl_xor(rmax, 32));
  // defer-rescale: only pay the O/l rescale when the max actually grew (>THR)
  if (rmax > m_run + 8.f) {
    const float al = exp2_hw(m_run - rmax);
    m_run = rmax;
    l_run *= al;
#pragma unroll
    for (int nd = 0; nd < 8; ++nd) oacc[nd] *= al;
  }
  float rs = 0.f;
#pragma unroll
  for (int nb = 0; nb < 4; ++nb)
#pragma unroll
    for (int r = 0; r < 4; ++r) {
      float e = 0.f;
      if (nb < nbp) {
        e = exp2_hw(p[nb][r] - m_run);       // bounded by 2^8
        rs += e;
      }
      p[nb][r] = e;
    }
  rs += __shfl_xor(rs, 16);
  rs += __shfl_xor(rs, 32);
  l_run += rs;
  // ---- pack P -> per-wave LDS (replaces bpermute gather) ----
  asm volatile("" ::: "memory");   // order after previous tile's Pl reads
#pragma unroll
  for (int nb = 0; nb < 4; ++nb) {
    uint2 u;
    u.x = pk_bf16(p[nb][0], p[nb][1]);
    u.y = pk_bf16(p[nb][2], p[nb][3]);
    *reinterpret_cast<uint2*>(Plw + c * 72 + nb * 16 + g * 4) = u;
  }
  asm volatile("" ::: "memory");   // cross-lane write->read ordering (in-order LDS pipe)
  // ---- PV over two 32-kv windows ----
  __builtin_amdgcn_s_setprio(1);
#pragma unroll
  for (int w = 0; w < 2; ++w)
    if (w * 2 < nbp) {
      bf16x8 pb = *(const bf16x8*)(Plw + c * 72 + w * 32 + g * 8);
#pragma unroll
      for (int nd = 0; nd < 8; ++nd) {
        bf16x8 vf = *(const bf16x8*)((const char*)Vt +
                      ((nd * 16 + c) * 72 + w * 32 + g * 8) * 2);
        oacc[nd] = __builtin_amdgcn_mfma_f32_16x16x32_bf16(vf, pb, oacc[nd], 0, 0, 0);
      }
    }
  __builtin_amdgcn_s_setprio(0);
}

__global__ __launch_bounds__(256) void attn_kernel(const unsigned short* __restrict__ qkv,
                                                   unsigned short* __restrict__ ob) {
  const int S = 2048;
  const int QKVS = 3072;                    // packed row stride
  __shared__ unsigned short Ks[64 * 128];   // linear rows of 256B, chunk-swizzled content
  __shared__ unsigned short Vt[128 * 72];   // V^T, rows padded to 72 elems (144B, 16B-aligned)
  __shared__ unsigned short Pl[4 * 16 * 72];// per-wave P^T scratch
  const int tid = threadIdx.x;
  const int lane = tid & 63;
  const int wave = tid >> 6;
  const int b = blockIdx.z, h = blockIdx.y;
  const int tiA = blockIdx.x, tiB = 31 - tiA;
  const int kvh = h >> 2;                   // rep = H/KV = 4
  const int c = lane & 15, g = lane >> 4;
  const int q0Aw = tiA * 64 + wave * 16;
  const int q0Bw = tiB * 64 + wave * 16;
  unsigned short* Plw = Pl + wave * 16 * 72;

  // Q fragments for both tiles (B-operand of swapped QK)
  bf16x8 qfA[4], qfB[4];
  {
    const unsigned short* qpA = qkv + (size_t)(b * S + q0Aw + c) * QKVS + h * 128 + g * 8;
    const unsigned short* qpB = qkv + (size_t)(b * S + q0Bw + c) * QKVS + h * 128 + g * 8;
#pragma unroll
    for (int kk = 0; kk < 4; ++kk) {
      qfA[kk] = *(const bf16x8*)(qpA + kk * 32);
      qfB[kk] = *(const bf16x8*)(qpB + kk * 32);
    }
  }
  f32x4 oaccA[8], oaccB[8];   // attn^T: d = 16*nd + 4g + reg, q = c
#pragma unroll
  for (int nd = 0; nd < 8; ++nd) {
    oaccA[nd] = (f32x4){0.f, 0.f, 0.f, 0.f};
    oaccB[nd] = (f32x4){0.f, 0.f, 0.f, 0.f};
  }
  float mA = -1e30f, lA = 0.f, mB = -1e30f, lB = 0.f;

  const int ntile = tiB + 1;
  for (int t = 0; t < ntile; ++t) {
    const int kv0 = t * 64;
    __syncthreads();   // previous tile's LDS reads done before overwrite
    // ---- stage K: global_load_lds, source chunk pre-swizzled (involution c ^= row&7) ----
#pragma unroll
    for (int i = 0; i < 4; ++i) {
      const int r0 = i * 16 + wave * 4;   // 4 rows (1KB) per wave-issue
      const int row = r0 + g;
      const int ch = c ^ (row & 7);
      const unsigned short* gk = qkv + (size_t)(b * S + kv0 + row) * QKVS + 2048 + kvh * 128 + ch * 8;
      gll16(gk, (char*)Ks + r0 * 256);
    }
    // ---- stage V^T: reg-staged transpose ----
#pragma unroll
    for (int ii = 0; ii < 4; ++ii) {
      const int d0 = wave * 32 + ii * 8;
      const unsigned short* gv = qkv + (size_t)(b * S + kv0 + lane) * QKVS + 2560 + kvh * 128 + d0;
      union { int4 i4; unsigned short u[8]; } vv;
      vv.i4 = *(const int4*)gv;
#pragma unroll
      for (int j = 0; j < 8; ++j) Vt[(d0 + j) * 72 + lane] = vv.u[j];
    }
    __syncthreads();
    // ---- compute: tile A (while in causal range), then tile B (always) ----
    if (t <= tiA) attn_tile(Ks, Vt, Plw, qfA, oaccA, mA, lA, kv0, q0Aw, c, g);
    attn_tile(Ks, Vt, Plw, qfB, oaccB, mB, lB, kv0, q0Bw, c, g);
  }

  // epilogue: attn[b, q, h, d] = oacc / l
  {
    const float inv = 1.f / lA;
    unsigned short* op = ob + ((size_t)(b * S + q0Aw + c) * 16 + h) * 128;
#pragma unroll
    for (int nd = 0; nd < 8; ++nd)
#pragma unroll
      for (int r = 0; r < 4; ++r)
        op[nd * 16 + g * 4 + r] = f2bf(oaccA[nd][r] * inv);
  }
  {
    const float inv = 1.f / lB;
    unsigned short* op = ob + ((size_t)(b * S + q0Bw + c) * 16 + h) * 128;
#pragma unroll
    for (int nd = 0; nd < 8; ++nd)
#pragma unroll
      for (int r = 0; r < 4; ++r)
        op[nd * 16 + g * 4 + r] = f2bf(oaccB[nd][r] * inv);
  }
}

// ---------------- launch ----------------
extern "C" void kernel_launch(void* const* d_in, const int* in_sizes, int n_in,
                              void* d_out, int out_size, void* d_ws, size_t ws_size,
                              hipStream_t stream) {
  (void)in_sizes; (void)n_in; (void)out_size; (void)ws_size;
  const float* x  = (const float*)d_in[0];
  const float* Wq = (const float*)d_in[1];
  const float* Wk = (const float*)d_in[2];
  const float* Wv = (const float*)d_in[3];
  const float* Wo = (const float*)d_in[4];
  float* out = (float*)d_out;

  const int B = 2, S = 2048, E = 2048;
  const int M = B * S;              // 4096
  const int KVDIM = 512;            // KV * D
  const int NQKV = E + 2 * KVDIM;   // 3072 packed

  char* p = (char*)d_ws;
  unsigned short* xb   = (unsigned short*)p; p += (size_t)M * E * 2;
  // wqb/wkb/wvb MUST stay contiguous in this order: they form the fused
  // B-operand (rows = output features of Wq || Wk || Wv).
  unsigned short* wqb  = (unsigned short*)p; p += (size_t)E * E * 2;
  unsigned short* wkb  = (unsigned short*)p; p += (size_t)KVDIM * E * 2;
  unsigned short* wvb  = (unsigned short*)p; p += (size_t)KVDIM * E * 2;
  unsigned short* wob  = (unsigned short*)p; p += (size_t)E * E * 2;
  unsigned short* qkvbuf = (unsigned short*)p; p += (size_t)M * NQKV * 2;  // packed per-row [Q|K|V]
  unsigned short* abuf   = (unsigned short*)p; p += (size_t)M * E * 2;

  {
    int n4;
    n4 = (M * E) / 4;     cvt_kernel<<<(n4 + 255) / 256, 256, 0, stream>>>(x,  xb,  n4);
    n4 = (E * E) / 4;     cvt_kernel<<<(n4 + 255) / 256, 256, 0, stream>>>(Wq, wqb, n4);
    n4 = (KVDIM * E) / 4; cvt_kernel<<<(n4 + 255) / 256, 256, 0, stream>>>(Wk, wkb, n4);
    n4 = (KVDIM * E) / 4; cvt_kernel<<<(n4 + 255) / 256, 256, 0, stream>>>(Wv, wvb, n4);
    n4 = (E * E) / 4;     cvt_kernel<<<(n4 + 255) / 256, 256, 0, stream>>>(Wo, wob, n4);
  }

  dim3 blk(256);
  // fused QKV projection: grid 32x24 = 768 blocks (3/CU) vs 512+128+128
  gemm_bt<unsigned short><<<dim3(M / 128, NQKV / 128), blk, 0, stream>>>(xb, wqb, qkvbuf, M, NQKV, E);
  attn_kernel<<<dim3(16, 16, B), blk, 0, stream>>>(qkvbuf, abuf);
  gemm_bt<float><<<dim3(M / 128, E / 128), blk, 0, stream>>>(abuf, wob, out, M, E, E);
}